// Round 1
// baseline (545.241 us; speedup 1.0000x reference)
//
#include <hip/hip_runtime.h>
#include <hip/hip_bf16.h>

// ComplexAttention: B=2, L=2048, D=1024, H=16, HD=64, SCALE=0.125
// Pipeline: pack(x,w) -> bf16 GEMM (QKV, V stored transposed) -> flash attn -> bf16 GEMM (+bias, fp32 out)

using f32x4  = __attribute__((ext_vector_type(4))) float;
using short8 = __attribute__((ext_vector_type(8))) short;   // 8 bf16 = 4 VGPRs (MFMA A/B frag)
using bf16_t = __hip_bfloat16;

#define AS1 __attribute__((address_space(1)))
#define AS3 __attribute__((address_space(3)))

__device__ __forceinline__ void gload_lds16(const bf16_t* g, bf16_t* l) {
  // async global->LDS, 16B per lane; LDS dest is wave-uniform base + lane*16
  __builtin_amdgcn_global_load_lds((const AS1 unsigned int*)g, (AS3 unsigned int*)l, 16, 0, 0);
}

__device__ __forceinline__ unsigned short bfbits(float f) {
  union { bf16_t h; unsigned short u; } c; c.h = __float2bfloat16(f); return c.u;
}

// ---------------------------------------------------------------- pack kernels
__global__ void pack_x_k(const float* __restrict__ xr, const float* __restrict__ xi,
                         bf16_t* __restrict__ out) {
  const int total4 = 4096 * 2048 / 4;
  for (int idx = blockIdx.x * blockDim.x + threadIdx.x; idx < total4;
       idx += gridDim.x * blockDim.x) {
    int m = idx >> 9, k = (idx & 511) * 4;
    const float* src = (k < 1024) ? (xr + (size_t)m * 1024 + k)
                                  : (xi + (size_t)m * 1024 + (k - 1024));
    float4 v = *(const float4*)src;
    unsigned int lo = (unsigned)bfbits(v.x) | ((unsigned)bfbits(v.y) << 16);
    unsigned int hi = (unsigned)bfbits(v.z) | ((unsigned)bfbits(v.w) << 16);
    *(uint2*)(out + (size_t)idx * 4) = make_uint2(lo, hi);
  }
}

// Wqkv: 6144 rows x 2048 cols. Sections of 1024 rows: Qr,Qi,Kr,Ki,Vr,Vi.
// row n of Qr = [wq_r[n,:] | -wq_i[n,:]], Qi = [wq_i[n,:] | wq_r[n,:]], etc.
__global__ void pack_wqkv_k(const float* __restrict__ wqr, const float* __restrict__ wqi,
                            const float* __restrict__ wkr, const float* __restrict__ wki,
                            const float* __restrict__ wvr, const float* __restrict__ wvi,
                            bf16_t* __restrict__ out) {
  const int total4 = 6144 * 2048 / 4;
  for (int idx = blockIdx.x * blockDim.x + threadIdx.x; idx < total4;
       idx += gridDim.x * blockDim.x) {
    int row = idx >> 9, k = (idx & 511) * 4;
    int sec = row >> 10, r1 = row & 1023;
    bool lowk = (k < 1024);
    int kk = lowk ? k : (k - 1024);
    const float* base = wqr; float sg = 1.f;
    switch (sec) {
      case 0: base = lowk ? wqr : wqi; sg = lowk ? 1.f : -1.f; break;
      case 1: base = lowk ? wqi : wqr; break;
      case 2: base = lowk ? wkr : wki; sg = lowk ? 1.f : -1.f; break;
      case 3: base = lowk ? wki : wkr; break;
      case 4: base = lowk ? wvr : wvi; sg = lowk ? 1.f : -1.f; break;
      case 5: base = lowk ? wvi : wvr; break;
    }
    float4 v = *(const float4*)(base + (size_t)r1 * 1024 + kk);
    unsigned int lo = (unsigned)bfbits(v.x * sg) | ((unsigned)bfbits(v.y * sg) << 16);
    unsigned int hi = (unsigned)bfbits(v.z * sg) | ((unsigned)bfbits(v.w * sg) << 16);
    *(uint2*)(out + (size_t)idx * 4) = make_uint2(lo, hi);
  }
}

__global__ void pack_wo_k(const float* __restrict__ wor, const float* __restrict__ woi,
                          bf16_t* __restrict__ out) {
  const int total4 = 2048 * 2048 / 4;
  for (int idx = blockIdx.x * blockDim.x + threadIdx.x; idx < total4;
       idx += gridDim.x * blockDim.x) {
    int row = idx >> 9, k = (idx & 511) * 4;
    int sec = row >> 10, r1 = row & 1023;
    bool lowk = (k < 1024);
    int kk = lowk ? k : (k - 1024);
    const float* base; float sg = 1.f;
    if (sec == 0) { base = lowk ? wor : woi; sg = lowk ? 1.f : -1.f; }
    else          { base = lowk ? woi : wor; }
    float4 v = *(const float4*)(base + (size_t)r1 * 1024 + kk);
    unsigned int lo = (unsigned)bfbits(v.x * sg) | ((unsigned)bfbits(v.y * sg) << 16);
    unsigned int hi = (unsigned)bfbits(v.z * sg) | ((unsigned)bfbits(v.w * sg) << 16);
    *(uint2*)(out + (size_t)idx * 4) = make_uint2(lo, hi);
  }
}

// ---------------------------------------------------------------- GEMM core (m97 structure)
// C[m,n] = sum_k A[m,k]*W[n,k], A: Mx2048, W: Nx2048, both bf16 row-major. 128x128 tile, BK=32.
__device__ __forceinline__ void gemm_core(const bf16_t* __restrict__ A,
                                          const bf16_t* __restrict__ W,
                                          int m0, int n0, f32x4 (&acc)[4][4]) {
  __shared__ __align__(16) bf16_t sA[128 * 32];
  __shared__ __align__(16) bf16_t sB[128 * 32];
  const int tid = threadIdx.x;
  const int lane = tid & 63, w = tid >> 6;
  const int wr = w >> 1, wc = w & 1;
  const int quad = lane >> 4, m16 = lane & 15;
  const int c0 = tid, c1 = tid + 256;
  const int r0 = c0 >> 2, o0 = (c0 & 3) * 8;
  const int r1 = c1 >> 2, o1 = (c1 & 3) * 8;
  for (int k0 = 0; k0 < 2048; k0 += 32) {
    __syncthreads();
    gload_lds16(A + (size_t)(m0 + r0) * 2048 + k0 + o0, sA + c0 * 8);
    gload_lds16(A + (size_t)(m0 + r1) * 2048 + k0 + o1, sA + c1 * 8);
    gload_lds16(W + (size_t)(n0 + r0) * 2048 + k0 + o0, sB + c0 * 8);
    gload_lds16(W + (size_t)(n0 + r1) * 2048 + k0 + o1, sB + c1 * 8);
    __syncthreads();
    short8 af[4], bf[4];
#pragma unroll
    for (int i = 0; i < 4; ++i)
      af[i] = *(const short8*)(sA + (wr * 64 + i * 16 + m16) * 32 + quad * 8);
#pragma unroll
    for (int j = 0; j < 4; ++j)
      bf[j] = *(const short8*)(sB + (wc * 64 + j * 16 + m16) * 32 + quad * 8);
#pragma unroll
    for (int i = 0; i < 4; ++i)
#pragma unroll
      for (int j = 0; j < 4; ++j)
        acc[i][j] = __builtin_amdgcn_mfma_f32_16x16x32_bf16(af[i], bf[j], acc[i][j], 0, 0, 0);
  }
}

// QKV GEMM: N=6144. cols 0..4095 -> qk buf [4096][4096] (Qr|Qi|Kr|Ki), cols 4096..6143 -> V
// transposed: vt[b*2048 + h*128 + ri*64 + d][seq]  (bf16, rows of 2048)
__global__ __launch_bounds__(256) void gemm_qkv_k(const bf16_t* __restrict__ A,
                                                  const bf16_t* __restrict__ W,
                                                  bf16_t* __restrict__ qk,
                                                  bf16_t* __restrict__ vt) {
  f32x4 acc[4][4] = {};
  const int m0 = blockIdx.x * 128, n0 = blockIdx.y * 128;
  gemm_core(A, W, m0, n0, acc);
  const int lane = threadIdx.x & 63, w = threadIdx.x >> 6;
  const int wr = w >> 1, wc = w & 1, quad = lane >> 4, m16 = lane & 15;
#pragma unroll
  for (int i = 0; i < 4; ++i) {
    const int rowb = m0 + wr * 64 + i * 16 + quad * 4;  // C/D row = quad*4 + reg
#pragma unroll
    for (int j = 0; j < 4; ++j) {
      const int col = n0 + wc * 64 + j * 16 + m16;      // C/D col = lane&15
      if (col < 4096) {
#pragma unroll
        for (int r = 0; r < 4; ++r)
          qk[(size_t)(rowb + r) * 4096 + col] = __float2bfloat16(acc[i][j][r]);
      } else {
        const int vcol = col - 4096;
        const int ri = vcol >> 10, dfeat = vcol & 1023;
        const int b = rowb >> 11, seq = rowb & 2047;
        const size_t vrow = (size_t)(b * 2048 + (dfeat >> 6) * 128 + ri * 64 + (dfeat & 63));
        unsigned int lo = (unsigned)bfbits(acc[i][j][0]) | ((unsigned)bfbits(acc[i][j][1]) << 16);
        unsigned int hi = (unsigned)bfbits(acc[i][j][2]) | ((unsigned)bfbits(acc[i][j][3]) << 16);
        *(uint2*)(vt + vrow * 2048 + seq) = make_uint2(lo, hi);  // 4 consecutive seq, 8B aligned
      }
    }
  }
}

// Output GEMM: N=2048 ([yr|yi]), fp32 out + bias. d_out = yr(4096x1024) then yi(4096x1024).
__global__ __launch_bounds__(256) void gemm_out_k(const bf16_t* __restrict__ A,
                                                  const bf16_t* __restrict__ W,
                                                  const float* __restrict__ bor,
                                                  const float* __restrict__ boi,
                                                  float* __restrict__ out) {
  f32x4 acc[4][4] = {};
  const int m0 = blockIdx.x * 128, n0 = blockIdx.y * 128;
  gemm_core(A, W, m0, n0, acc);
  const int lane = threadIdx.x & 63, w = threadIdx.x >> 6;
  const int wr = w >> 1, wc = w & 1, quad = lane >> 4, m16 = lane & 15;
#pragma unroll
  for (int i = 0; i < 4; ++i) {
    const int rowb = m0 + wr * 64 + i * 16 + quad * 4;
#pragma unroll
    for (int j = 0; j < 4; ++j) {
      const int col = n0 + wc * 64 + j * 16 + m16;
      float bias; float* op;
      if (col < 1024) { bias = bor[col]; op = out + col; }
      else            { bias = boi[col - 1024]; op = out + 4194304 + (col - 1024); }
#pragma unroll
      for (int r = 0; r < 4; ++r)
        op[(size_t)(rowb + r) * 1024] = acc[i][j][r] + bias;
    }
  }
}

// ---------------------------------------------------------------- flash attention
// grid (L/64, B*H). Block=4 waves; wave w owns q rows [q0+w*16, +16). Head-dim 128 (Qr|Qi).
// S = Qcat·Kcat^T * 0.125, causal, online softmax; O += P·Vcat via P LDS round-trip.
__global__ __launch_bounds__(256) void attn_k(const bf16_t* __restrict__ qk,
                                              const bf16_t* __restrict__ vt,
                                              bf16_t* __restrict__ acat) {
  __shared__ __align__(16) bf16_t sK[32 * 136];   // Kcat tile, row stride 136 (bank-spread)
  __shared__ __align__(16) bf16_t sV[128 * 40];   // V^T tile: [d][k], row stride 40
  __shared__ __align__(16) bf16_t sP[4][16 * 40]; // per-wave P, row stride 40
  const int tid = threadIdx.x, lane = tid & 63, w = tid >> 6;
  const int quad = lane >> 4, m16 = lane & 15;
  const int q0 = blockIdx.x * 64;
  const int bh = blockIdx.y, b = bh >> 4, h = bh & 15;
  const size_t qkrow0 = (size_t)b * 2048;

  // Q fragments (A-operand layout: m=lane&15, k=quad*8+j), k-chunks of 32 over Dc=128
  short8 qf[4];
  {
    const bf16_t* qbase = qk + (qkrow0 + q0 + w * 16 + m16) * 4096;
#pragma unroll
    for (int kk = 0; kk < 4; ++kk) {
      const int col = (kk >> 1) * 1024 + h * 64 + (kk & 1) * 32 + quad * 8;
      qf[kk] = *(const short8*)(qbase + col);
    }
  }
  f32x4 o[8];
#pragma unroll
  for (int j = 0; j < 8; ++j) o[j] = (f32x4){0.f, 0.f, 0.f, 0.f};
  float ms[4], ls[4];
#pragma unroll
  for (int r = 0; r < 4; ++r) { ms[r] = -1e30f; ls[r] = 0.f; }
  const int q_hi = q0 + w * 16 + 15;
  const int nT = (q0 >> 5) + 2;

  for (int t = 0; t < nT; ++t) {
    const int k0 = t * 32;
    __syncthreads();
    // stage Kcat tile: 32 rows x 128 (Kr|Ki per head)
#pragma unroll
    for (int it = 0; it < 2; ++it) {
      const int c = it * 256 + tid;
      const int row = c >> 4, half = (c >> 3) & 1, off = (c & 7) * 8;
      const bf16_t* g = qk + (qkrow0 + k0 + row) * 4096 + 2048 + half * 1024 + h * 64 + off;
      *(int4*)(sK + row * 136 + half * 64 + off) = *(const int4*)g;
    }
    // stage V^T tile: 128 rows (d) x 32 (k)
#pragma unroll
    for (int it = 0; it < 2; ++it) {
      const int c = it * 256 + tid;
      const int d = c >> 2, kc = c & 3;
      const bf16_t* g = vt + ((size_t)bh * 128 + d) * 2048 + k0 + kc * 8;
      *(int4*)(sV + d * 40 + kc * 8) = *(const int4*)g;
    }
    __syncthreads();
    if (k0 <= q_hi) {  // wave-uniform causal skip (still joins barriers)
      f32x4 sj[2];
#pragma unroll
      for (int jt = 0; jt < 2; ++jt) {
        f32x4 a = (f32x4){0.f, 0.f, 0.f, 0.f};
#pragma unroll
        for (int kk = 0; kk < 4; ++kk) {
          short8 bfr = *(const short8*)(sK + (jt * 16 + m16) * 136 + kk * 32 + quad * 8);
          a = __builtin_amdgcn_mfma_f32_16x16x32_bf16(qf[kk], bfr, a, 0, 0, 0);
        }
        sj[jt] = a;
      }
      const int qg = q0 + w * 16 + quad * 4;
      const int kc0 = k0 + m16, kc1 = k0 + 16 + m16;
      float alpha[4];
#pragma unroll
      for (int r = 0; r < 4; ++r) {
        float s0 = sj[0][r] * 0.125f;
        float s1 = sj[1][r] * 0.125f;
        if (kc0 > qg + r) s0 = -1e30f;
        if (kc1 > qg + r) s1 = -1e30f;
        float rm = fmaxf(s0, s1);
        rm = fmaxf(rm, __shfl_xor(rm, 1));
        rm = fmaxf(rm, __shfl_xor(rm, 2));
        rm = fmaxf(rm, __shfl_xor(rm, 4));
        rm = fmaxf(rm, __shfl_xor(rm, 8));
        const float mn = fmaxf(ms[r], rm);
        const float al = __expf(ms[r] - mn);
        ms[r] = mn;
        bf16_t hp0 = __float2bfloat16(__expf(s0 - mn));
        bf16_t hp1 = __float2bfloat16(__expf(s1 - mn));
        float rs = __bfloat162float(hp0) + __bfloat162float(hp1);  // sum what we store
        rs += __shfl_xor(rs, 1);
        rs += __shfl_xor(rs, 2);
        rs += __shfl_xor(rs, 4);
        rs += __shfl_xor(rs, 8);
        ls[r] = ls[r] * al + rs;
        alpha[r] = al;
        sP[w][(quad * 4 + r) * 40 + m16] = hp0;
        sP[w][(quad * 4 + r) * 40 + 16 + m16] = hp1;
      }
#pragma unroll
      for (int j = 0; j < 8; ++j)
#pragma unroll
        for (int r = 0; r < 4; ++r) o[j][r] *= alpha[r];
      asm volatile("s_waitcnt lgkmcnt(0)" ::: "memory");  // P write->read, same wave
      short8 pf = *(const short8*)(&sP[w][m16 * 40 + quad * 8]);
#pragma unroll
      for (int j = 0; j < 8; ++j) {
        short8 vfr = *(const short8*)(sV + (j * 16 + m16) * 40 + quad * 8);
        o[j] = __builtin_amdgcn_mfma_f32_16x16x32_bf16(pf, vfr, o[j], 0, 0, 0);
      }
    }
  }
  // epilogue: normalize, write merged [B,L,2048] = [out_r | out_i]
  float inv[4];
#pragma unroll
  for (int r = 0; r < 4; ++r) inv[r] = 1.f / ls[r];
  const int rowb = q0 + w * 16 + quad * 4;
#pragma unroll
  for (int j = 0; j < 8; ++j) {
    const int d = j * 16 + m16;
    const int col = (d < 64) ? (h * 64 + d) : (1024 + h * 64 + (d - 64));
#pragma unroll
    for (int r = 0; r < 4; ++r)
      acat[((size_t)b * 2048 + rowb + r) * 2048 + col] = __float2bfloat16(o[j][r] * inv[r]);
  }
}

// ---------------------------------------------------------------- launch
extern "C" void kernel_launch(void* const* d_in, const int* in_sizes, int n_in,
                              void* d_out, int out_size, void* d_ws, size_t ws_size,
                              hipStream_t stream) {
  const float* xr  = (const float*)d_in[0];
  const float* xi  = (const float*)d_in[1];
  const float* wqr = (const float*)d_in[2];
  const float* wqi = (const float*)d_in[3];
  const float* wkr = (const float*)d_in[4];
  const float* wki = (const float*)d_in[5];
  const float* wvr = (const float*)d_in[6];
  const float* wvi = (const float*)d_in[7];
  const float* wor = (const float*)d_in[8];
  const float* woi = (const float*)d_in[9];
  const float* bor = (const float*)d_in[10];
  const float* boi = (const float*)d_in[11];
  float* out = (float*)d_out;

  char* ws = (char*)d_ws;
  bf16_t* Xcat = (bf16_t*)(ws);                   // 4096x2048   16 MB
  bf16_t* Wqkv = (bf16_t*)(ws + 16777216ull);     // 6144x2048   24 MB
  bf16_t* QKb  = (bf16_t*)(ws + 41943040ull);     // 4096x4096   32 MB
  bf16_t* Vt   = (bf16_t*)(ws + 75497472ull);     // 4096x2048   16 MB (V transposed)
  bf16_t* Acat = (bf16_t*)(ws + 92274688ull);     // 4096x2048   16 MB
  bf16_t* Wo   = (bf16_t*)(ws + 109051904ull);    // 2048x2048    8 MB

  pack_x_k<<<2048, 256, 0, stream>>>(xr, xi, Xcat);
  pack_wqkv_k<<<2048, 256, 0, stream>>>(wqr, wqi, wkr, wki, wvr, wvi, Wqkv);
  pack_wo_k<<<1024, 256, 0, stream>>>(wor, woi, Wo);
  gemm_qkv_k<<<dim3(32, 48), 256, 0, stream>>>(Xcat, Wqkv, QKb, Vt);
  attn_k<<<dim3(32, 32), 256, 0, stream>>>(QKb, Vt, Acat);
  gemm_out_k<<<dim3(32, 16), 256, 0, stream>>>(Acat, Wo, bor, boi, out);
}

// Round 2
// 404.716 us; speedup vs baseline: 1.3472x; 1.3472x over previous
//
#include <hip/hip_runtime.h>
#include <hip/hip_bf16.h>

// ComplexAttention: B=2, L=2048, D=1024, H=16, HD=64, SCALE=0.125
// Pipeline: pack(x,w) -> bf16 GEMM (QKV, Q pre-scaled, V stored transposed)
//           -> flash attn (paired q-tiles, fixed-max softmax, ones-row l) -> bf16 GEMM (+bias, fp32 out)

using f32x4  = __attribute__((ext_vector_type(4))) float;
using short8 = __attribute__((ext_vector_type(8))) short;   // 8 bf16 = 4 VGPRs (MFMA A/B frag)
using bf16_t = __hip_bfloat16;

#define AS1 __attribute__((address_space(1)))
#define AS3 __attribute__((address_space(3)))

__device__ __forceinline__ void gload_lds16(const bf16_t* g, bf16_t* l) {
  __builtin_amdgcn_global_load_lds((const AS1 unsigned int*)g, (AS3 unsigned int*)l, 16, 0, 0);
}

__device__ __forceinline__ unsigned short bfbits(float f) {
  union { bf16_t h; unsigned short u; } c; c.h = __float2bfloat16(f); return c.u;
}

// ---------------------------------------------------------------- pack kernels
__global__ void pack_x_k(const float* __restrict__ xr, const float* __restrict__ xi,
                         bf16_t* __restrict__ out) {
  const int total4 = 4096 * 2048 / 4;
  for (int idx = blockIdx.x * blockDim.x + threadIdx.x; idx < total4;
       idx += gridDim.x * blockDim.x) {
    int m = idx >> 9, k = (idx & 511) * 4;
    const float* src = (k < 1024) ? (xr + (size_t)m * 1024 + k)
                                  : (xi + (size_t)m * 1024 + (k - 1024));
    float4 v = *(const float4*)src;
    unsigned int lo = (unsigned)bfbits(v.x) | ((unsigned)bfbits(v.y) << 16);
    unsigned int hi = (unsigned)bfbits(v.z) | ((unsigned)bfbits(v.w) << 16);
    *(uint2*)(out + (size_t)idx * 4) = make_uint2(lo, hi);
  }
}

__global__ void pack_wqkv_k(const float* __restrict__ wqr, const float* __restrict__ wqi,
                            const float* __restrict__ wkr, const float* __restrict__ wki,
                            const float* __restrict__ wvr, const float* __restrict__ wvi,
                            bf16_t* __restrict__ out) {
  const int total4 = 6144 * 2048 / 4;
  for (int idx = blockIdx.x * blockDim.x + threadIdx.x; idx < total4;
       idx += gridDim.x * blockDim.x) {
    int row = idx >> 9, k = (idx & 511) * 4;
    int sec = row >> 10, r1 = row & 1023;
    bool lowk = (k < 1024);
    int kk = lowk ? k : (k - 1024);
    const float* base = wqr; float sg = 1.f;
    switch (sec) {
      case 0: base = lowk ? wqr : wqi; sg = lowk ? 1.f : -1.f; break;
      case 1: base = lowk ? wqi : wqr; break;
      case 2: base = lowk ? wkr : wki; sg = lowk ? 1.f : -1.f; break;
      case 3: base = lowk ? wki : wkr; break;
      case 4: base = lowk ? wvr : wvi; sg = lowk ? 1.f : -1.f; break;
      case 5: base = lowk ? wvi : wvr; break;
    }
    float4 v = *(const float4*)(base + (size_t)r1 * 1024 + kk);
    unsigned int lo = (unsigned)bfbits(v.x * sg) | ((unsigned)bfbits(v.y * sg) << 16);
    unsigned int hi = (unsigned)bfbits(v.z * sg) | ((unsigned)bfbits(v.w * sg) << 16);
    *(uint2*)(out + (size_t)idx * 4) = make_uint2(lo, hi);
  }
}

__global__ void pack_wo_k(const float* __restrict__ wor, const float* __restrict__ woi,
                          bf16_t* __restrict__ out) {
  const int total4 = 2048 * 2048 / 4;
  for (int idx = blockIdx.x * blockDim.x + threadIdx.x; idx < total4;
       idx += gridDim.x * blockDim.x) {
    int row = idx >> 9, k = (idx & 511) * 4;
    int sec = row >> 10, r1 = row & 1023;
    bool lowk = (k < 1024);
    int kk = lowk ? k : (k - 1024);
    const float* base; float sg = 1.f;
    if (sec == 0) { base = lowk ? wor : woi; sg = lowk ? 1.f : -1.f; }
    else          { base = lowk ? woi : wor; }
    float4 v = *(const float4*)(base + (size_t)r1 * 1024 + kk);
    unsigned int lo = (unsigned)bfbits(v.x * sg) | ((unsigned)bfbits(v.y * sg) << 16);
    unsigned int hi = (unsigned)bfbits(v.z * sg) | ((unsigned)bfbits(v.w * sg) << 16);
    *(uint2*)(out + (size_t)idx * 4) = make_uint2(lo, hi);
  }
}

// ---------------------------------------------------------------- GEMM core (m97 structure)
__device__ __forceinline__ void gemm_core(const bf16_t* __restrict__ A,
                                          const bf16_t* __restrict__ W,
                                          int m0, int n0, f32x4 (&acc)[4][4]) {
  __shared__ __align__(16) bf16_t sA[128 * 32];
  __shared__ __align__(16) bf16_t sB[128 * 32];
  const int tid = threadIdx.x;
  const int lane = tid & 63, w = tid >> 6;
  const int wr = w >> 1, wc = w & 1;
  const int quad = lane >> 4, m16 = lane & 15;
  const int c0 = tid, c1 = tid + 256;
  const int r0 = c0 >> 2, o0 = (c0 & 3) * 8;
  const int r1 = c1 >> 2, o1 = (c1 & 3) * 8;
  for (int k0 = 0; k0 < 2048; k0 += 32) {
    __syncthreads();
    gload_lds16(A + (size_t)(m0 + r0) * 2048 + k0 + o0, sA + c0 * 8);
    gload_lds16(A + (size_t)(m0 + r1) * 2048 + k0 + o1, sA + c1 * 8);
    gload_lds16(W + (size_t)(n0 + r0) * 2048 + k0 + o0, sB + c0 * 8);
    gload_lds16(W + (size_t)(n0 + r1) * 2048 + k0 + o1, sB + c1 * 8);
    __syncthreads();
    short8 af[4], bf[4];
#pragma unroll
    for (int i = 0; i < 4; ++i)
      af[i] = *(const short8*)(sA + (wr * 64 + i * 16 + m16) * 32 + quad * 8);
#pragma unroll
    for (int j = 0; j < 4; ++j)
      bf[j] = *(const short8*)(sB + (wc * 64 + j * 16 + m16) * 32 + quad * 8);
#pragma unroll
    for (int i = 0; i < 4; ++i)
#pragma unroll
      for (int j = 0; j < 4; ++j)
        acc[i][j] = __builtin_amdgcn_mfma_f32_16x16x32_bf16(af[i], bf[j], acc[i][j], 0, 0, 0);
  }
}

// QKV GEMM: N=6144. cols 0..4095 -> qk buf [4096][4096] (Qr|Qi|Kr|Ki), Q pre-scaled by 0.125.
// cols 4096..6143 -> V transposed: vt[b*2048 + h*128 + ri*64 + d][seq]
__global__ __launch_bounds__(256) void gemm_qkv_k(const bf16_t* __restrict__ A,
                                                  const bf16_t* __restrict__ W,
                                                  bf16_t* __restrict__ qk,
                                                  bf16_t* __restrict__ vt) {
  f32x4 acc[4][4] = {};
  const int m0 = blockIdx.x * 128, n0 = blockIdx.y * 128;
  gemm_core(A, W, m0, n0, acc);
  const int lane = threadIdx.x & 63, w = threadIdx.x >> 6;
  const int wr = w >> 1, wc = w & 1, quad = lane >> 4, m16 = lane & 15;
#pragma unroll
  for (int i = 0; i < 4; ++i) {
    const int rowb = m0 + wr * 64 + i * 16 + quad * 4;
#pragma unroll
    for (int j = 0; j < 4; ++j) {
      const int col = n0 + wc * 64 + j * 16 + m16;
      if (col < 4096) {
        const float sc = (col < 2048) ? 0.125f : 1.f;  // pre-scale Q by SCALE
#pragma unroll
        for (int r = 0; r < 4; ++r)
          qk[(size_t)(rowb + r) * 4096 + col] = __float2bfloat16(acc[i][j][r] * sc);
      } else {
        const int vcol = col - 4096;
        const int ri = vcol >> 10, dfeat = vcol & 1023;
        const int b = rowb >> 11, seq = rowb & 2047;
        const size_t vrow = (size_t)(b * 2048 + (dfeat >> 6) * 128 + ri * 64 + (dfeat & 63));
        unsigned int lo = (unsigned)bfbits(acc[i][j][0]) | ((unsigned)bfbits(acc[i][j][1]) << 16);
        unsigned int hi = (unsigned)bfbits(acc[i][j][2]) | ((unsigned)bfbits(acc[i][j][3]) << 16);
        *(uint2*)(vt + vrow * 2048 + seq) = make_uint2(lo, hi);
      }
    }
  }
}

// Output GEMM: N=2048 ([yr|yi]), fp32 out + bias.
__global__ __launch_bounds__(256) void gemm_out_k(const bf16_t* __restrict__ A,
                                                  const bf16_t* __restrict__ W,
                                                  const float* __restrict__ bor,
                                                  const float* __restrict__ boi,
                                                  float* __restrict__ out) {
  f32x4 acc[4][4] = {};
  const int m0 = blockIdx.x * 128, n0 = blockIdx.y * 128;
  gemm_core(A, W, m0, n0, acc);
  const int lane = threadIdx.x & 63, w = threadIdx.x >> 6;
  const int wr = w >> 1, wc = w & 1, quad = lane >> 4, m16 = lane & 15;
#pragma unroll
  for (int i = 0; i < 4; ++i) {
    const int rowb = m0 + wr * 64 + i * 16 + quad * 4;
#pragma unroll
    for (int j = 0; j < 4; ++j) {
      const int col = n0 + wc * 64 + j * 16 + m16;
      float bias; float* op;
      if (col < 1024) { bias = bor[col]; op = out + col; }
      else            { bias = boi[col - 1024]; op = out + 4194304 + (col - 1024); }
#pragma unroll
      for (int r = 0; r < 4; ++r)
        op[(size_t)(rowb + r) * 1024] = acc[i][j][r] + bias;
    }
  }
}

// ---------------------------------------------------------------- flash attention v2
// grid (16, B*H): block x handles q-subtiles A = x*64.. and B = (31-x)*64.. against a SHARED
// staged K/V tile (joint k-loop, BK=64). Fixed-max softmax (scores bounded; exp fp32-safe),
// row-sum l via ones-row MFMA (V row 128 = 1, rows 129..143 = 0). 4 waves; wave w owns
// rows [sub + w*16, +16) of each subtile.
__global__ __launch_bounds__(256, 2) void attn_k(const bf16_t* __restrict__ qk,
                                                 const bf16_t* __restrict__ vt,
                                                 bf16_t* __restrict__ acat) {
  __shared__ __align__(16) bf16_t sK[64 * 136];      // 64 k-rows x 128 d, stride 136
  __shared__ __align__(16) bf16_t sV[144 * 72];      // 128 d-rows + ones/zeros, x 64 k, stride 72
  __shared__ __align__(16) bf16_t sP[4][2][16 * 72]; // [wave][part] 16 q x 64 k, stride 72
  const int tid = threadIdx.x, lane = tid & 63, w = tid >> 6;
  const int quad = lane >> 4, m16 = lane & 15;
  const int x = blockIdx.x, bh = blockIdx.y, b = bh >> 4, h = bh & 15;
  const size_t qkrow0 = (size_t)b * 2048;
  const int qA = x * 64, qB = (31 - x) * 64;
  const int nT = 32 - x;

  // preset sV rows 128..143: row 128 = ones, rest zeros (ones-row l trick)
  {
    const int rr = tid >> 4, cb = (tid & 15) * 4;
    const bf16_t v = __float2bfloat16(rr == 0 ? 1.f : 0.f);
#pragma unroll
    for (int i = 0; i < 4; ++i) sV[(128 + rr) * 72 + cb + i] = v;
  }

  // Q fragments for both subtiles (A-operand: m=lane&15, k=quad*8+j), d-chunks of 32
  short8 qfA[4], qfB[4];
  {
    const bf16_t* qa = qk + (qkrow0 + qA + w * 16 + m16) * 4096;
    const bf16_t* qb = qk + (qkrow0 + qB + w * 16 + m16) * 4096;
#pragma unroll
    for (int kk = 0; kk < 4; ++kk) {
      const int col = (kk >> 1) * 1024 + h * 64 + (kk & 1) * 32 + quad * 8;
      qfA[kk] = *(const short8*)(qa + col);
      qfB[kk] = *(const short8*)(qb + col);
    }
  }
  f32x4 oA[9], oB[9];
#pragma unroll
  for (int j = 0; j < 9; ++j) { oA[j] = (f32x4){0.f,0.f,0.f,0.f}; oB[j] = (f32x4){0.f,0.f,0.f,0.f}; }

  const int qrowA = qA + w * 16 + quad * 4;  // global q of reg r=0
  const int qrowB = qB + w * 16 + quad * 4;

  for (int t = 0; t < nT; ++t) {
    const int k0 = t * 64;
    __syncthreads();
    // stage K tile: 64 rows x 128 (Kr|Ki of head h)
#pragma unroll
    for (int it = 0; it < 4; ++it) {
      const int c = it * 256 + tid;
      const int row = c >> 4, half = (c >> 3) & 1, o8 = (c & 7) * 8;
      *(int4*)(sK + row * 136 + half * 64 + o8) =
          *(const int4*)(qk + (qkrow0 + k0 + row) * 4096 + 2048 + half * 1024 + h * 64 + o8);
    }
    // stage V^T tile: 128 d-rows x 64 k
#pragma unroll
    for (int it = 0; it < 4; ++it) {
      const int c = it * 256 + tid;
      const int d = c >> 3, k8 = (c & 7) * 8;
      *(int4*)(sV + d * 72 + k8) = *(const int4*)(vt + ((size_t)bh * 128 + d) * 2048 + k0 + k8);
    }
    __syncthreads();

    const bool aAct = (t <= x);
    const bool dgA = (t == x), dgB = (t == nT - 1);

    // ---- S = Qs·K^T (Q pre-scaled); joint over both subtiles per K-frag read
    f32x4 sAv[4], sBv[4];
    if (aAct) {
#pragma unroll
      for (int jt = 0; jt < 4; ++jt) {
        f32x4 a1 = (f32x4){0.f,0.f,0.f,0.f}, a2 = (f32x4){0.f,0.f,0.f,0.f};
#pragma unroll
        for (int kk = 0; kk < 4; ++kk) {
          short8 kf = *(const short8*)(sK + (jt * 16 + m16) * 136 + kk * 32 + quad * 8);
          a1 = __builtin_amdgcn_mfma_f32_16x16x32_bf16(qfA[kk], kf, a1, 0, 0, 0);
          a2 = __builtin_amdgcn_mfma_f32_16x16x32_bf16(qfB[kk], kf, a2, 0, 0, 0);
        }
        sAv[jt] = a1; sBv[jt] = a2;
      }
    } else {
#pragma unroll
      for (int jt = 0; jt < 4; ++jt) {
        f32x4 a2 = (f32x4){0.f,0.f,0.f,0.f};
#pragma unroll
        for (int kk = 0; kk < 4; ++kk) {
          short8 kf = *(const short8*)(sK + (jt * 16 + m16) * 136 + kk * 32 + quad * 8);
          a2 = __builtin_amdgcn_mfma_f32_16x16x32_bf16(qfB[kk], kf, a2, 0, 0, 0);
        }
        sBv[jt] = a2;
      }
    }

    // ---- fixed-max softmax: P = exp(S), write to per-wave sP (C-layout -> A-layout via LDS)
    if (aAct) {
      bf16_t* pw = sP[w][0];
#pragma unroll
      for (int jt = 0; jt < 4; ++jt)
#pragma unroll
        for (int r = 0; r < 4; ++r) {
          float s = sAv[jt][r];
          if (dgA && (k0 + jt * 16 + m16 > qrowA + r)) s = -1e30f;
          pw[(quad * 4 + r) * 72 + jt * 16 + m16] = __float2bfloat16(__expf(s));
        }
    }
    {
      bf16_t* pw = sP[w][1];
#pragma unroll
      for (int jt = 0; jt < 4; ++jt)
#pragma unroll
        for (int r = 0; r < 4; ++r) {
          float s = sBv[jt][r];
          if (dgB && (k0 + jt * 16 + m16 > qrowB + r)) s = -1e30f;
          pw[(quad * 4 + r) * 72 + jt * 16 + m16] = __float2bfloat16(__expf(s));
        }
    }
    asm volatile("s_waitcnt lgkmcnt(0)" ::: "memory");  // own-wave P write->read

    // ---- O += P·V (j=8 is the ones-row -> row sums l); joint per V-frag read
    if (aAct) {
#pragma unroll
      for (int kc = 0; kc < 2; ++kc) {
        short8 pA = *(const short8*)(sP[w][0] + m16 * 72 + kc * 32 + quad * 8);
        short8 pB = *(const short8*)(sP[w][1] + m16 * 72 + kc * 32 + quad * 8);
#pragma unroll
        for (int j = 0; j < 9; ++j) {
          short8 vf = *(const short8*)(sV + (j * 16 + m16) * 72 + kc * 32 + quad * 8);
          oA[j] = __builtin_amdgcn_mfma_f32_16x16x32_bf16(pA, vf, oA[j], 0, 0, 0);
          oB[j] = __builtin_amdgcn_mfma_f32_16x16x32_bf16(pB, vf, oB[j], 0, 0, 0);
        }
      }
    } else {
#pragma unroll
      for (int kc = 0; kc < 2; ++kc) {
        short8 pB = *(const short8*)(sP[w][1] + m16 * 72 + kc * 32 + quad * 8);
#pragma unroll
        for (int j = 0; j < 9; ++j) {
          short8 vf = *(const short8*)(sV + (j * 16 + m16) * 72 + kc * 32 + quad * 8);
          oB[j] = __builtin_amdgcn_mfma_f32_16x16x32_bf16(pB, vf, oB[j], 0, 0, 0);
        }
      }
    }
  }

  // ---- epilogue: l broadcast from lane (quad,0), normalize, write [B,L,2048]=[out_r|out_i]
#pragma unroll
  for (int part = 0; part < 2; ++part) {
    f32x4* o = part ? oB : oA;
    const int qrow = part ? qrowB : qrowA;
    float inv[4];
#pragma unroll
    for (int r = 0; r < 4; ++r)
      inv[r] = 1.f / __shfl(o[8][r], lane & 48);
#pragma unroll
    for (int j = 0; j < 8; ++j) {
      const int d = j * 16 + m16;
      const int col = (d < 64) ? (h * 64 + d) : (1024 + h * 64 + (d - 64));
#pragma unroll
      for (int r = 0; r < 4; ++r)
        acat[((size_t)b * 2048 + qrow + r) * 2048 + col] = __float2bfloat16(o[j][r] * inv[r]);
    }
  }
}

// ---------------------------------------------------------------- launch
extern "C" void kernel_launch(void* const* d_in, const int* in_sizes, int n_in,
                              void* d_out, int out_size, void* d_ws, size_t ws_size,
                              hipStream_t stream) {
  const float* xr  = (const float*)d_in[0];
  const float* xi  = (const float*)d_in[1];
  const float* wqr = (const float*)d_in[2];
  const float* wqi = (const float*)d_in[3];
  const float* wkr = (const float*)d_in[4];
  const float* wki = (const float*)d_in[5];
  const float* wvr = (const float*)d_in[6];
  const float* wvi = (const float*)d_in[7];
  const float* wor = (const float*)d_in[8];
  const float* woi = (const float*)d_in[9];
  const float* bor = (const float*)d_in[10];
  const float* boi = (const float*)d_in[11];
  float* out = (float*)d_out;

  char* ws = (char*)d_ws;
  bf16_t* Xcat = (bf16_t*)(ws);                   // 4096x2048   16 MB
  bf16_t* Wqkv = (bf16_t*)(ws + 16777216ull);     // 6144x2048   24 MB
  bf16_t* QKb  = (bf16_t*)(ws + 41943040ull);     // 4096x4096   32 MB
  bf16_t* Vt   = (bf16_t*)(ws + 75497472ull);     // 4096x2048   16 MB (V transposed)
  bf16_t* Acat = (bf16_t*)(ws + 92274688ull);     // 4096x2048   16 MB
  bf16_t* Wo   = (bf16_t*)(ws + 109051904ull);    // 2048x2048    8 MB

  pack_x_k<<<2048, 256, 0, stream>>>(xr, xi, Xcat);
  pack_wqkv_k<<<2048, 256, 0, stream>>>(wqr, wqi, wkr, wki, wvr, wvi, Wqkv);
  pack_wo_k<<<1024, 256, 0, stream>>>(wor, woi, Wo);
  gemm_qkv_k<<<dim3(32, 48), 256, 0, stream>>>(Xcat, Wqkv, QKb, Vt);
  attn_k<<<dim3(16, 32), 256, 0, stream>>>(QKb, Vt, Acat);
  gemm_out_k<<<dim3(32, 16), 256, 0, stream>>>(Acat, Wo, bor, boi, out);
}

// Round 3
// 400.612 us; speedup vs baseline: 1.3610x; 1.0102x over previous
//
#include <hip/hip_runtime.h>
#include <hip/hip_bf16.h>

// ComplexAttention: B=2, L=2048, D=1024, H=16, HD=64, SCALE=0.125
// Pipeline: pack(x,w) -> bf16 GEMM BK=64 (QKV, Q pre-scaled, V stored transposed)
//           -> flash attn (paired q-tiles, fixed-max softmax, ones-row l, async staging)
//           -> bf16 GEMM (+bias, fp32 out)
// All LDS tiles staged via global_load_lds(16B) with XOR-16B-chunk swizzle
// (chunk' = chunk ^ (row&7)) folded into the GLOBAL address so LDS stays
// contiguous (wave-uniform base + lane*16 contract) yet frag reads are ~conflict-free.

using f32x4  = __attribute__((ext_vector_type(4))) float;
using short8 = __attribute__((ext_vector_type(8))) short;   // 8 bf16 = 4 VGPRs (MFMA A/B frag)
using bf16_t = __hip_bfloat16;

#define AS1 __attribute__((address_space(1)))
#define AS3 __attribute__((address_space(3)))

__device__ __forceinline__ void gload_lds16(const bf16_t* g, bf16_t* l) {
  __builtin_amdgcn_global_load_lds((const AS1 unsigned int*)g, (AS3 unsigned int*)l, 16, 0, 0);
}

__device__ __forceinline__ unsigned short bfbits(float f) {
  union { bf16_t h; unsigned short u; } c; c.h = __float2bfloat16(f); return c.u;
}

// ---------------------------------------------------------------- pack kernels
__global__ void pack_x_k(const float* __restrict__ xr, const float* __restrict__ xi,
                         bf16_t* __restrict__ out) {
  const int total4 = 4096 * 2048 / 4;
  for (int idx = blockIdx.x * blockDim.x + threadIdx.x; idx < total4;
       idx += gridDim.x * blockDim.x) {
    int m = idx >> 9, k = (idx & 511) * 4;
    const float* src = (k < 1024) ? (xr + (size_t)m * 1024 + k)
                                  : (xi + (size_t)m * 1024 + (k - 1024));
    float4 v = *(const float4*)src;
    unsigned int lo = (unsigned)bfbits(v.x) | ((unsigned)bfbits(v.y) << 16);
    unsigned int hi = (unsigned)bfbits(v.z) | ((unsigned)bfbits(v.w) << 16);
    *(uint2*)(out + (size_t)idx * 4) = make_uint2(lo, hi);
  }
}

__global__ void pack_wqkv_k(const float* __restrict__ wqr, const float* __restrict__ wqi,
                            const float* __restrict__ wkr, const float* __restrict__ wki,
                            const float* __restrict__ wvr, const float* __restrict__ wvi,
                            bf16_t* __restrict__ out) {
  const int total4 = 6144 * 2048 / 4;
  for (int idx = blockIdx.x * blockDim.x + threadIdx.x; idx < total4;
       idx += gridDim.x * blockDim.x) {
    int row = idx >> 9, k = (idx & 511) * 4;
    int sec = row >> 10, r1 = row & 1023;
    bool lowk = (k < 1024);
    int kk = lowk ? k : (k - 1024);
    const float* base = wqr; float sg = 1.f;
    switch (sec) {
      case 0: base = lowk ? wqr : wqi; sg = lowk ? 1.f : -1.f; break;
      case 1: base = lowk ? wqi : wqr; break;
      case 2: base = lowk ? wkr : wki; sg = lowk ? 1.f : -1.f; break;
      case 3: base = lowk ? wki : wkr; break;
      case 4: base = lowk ? wvr : wvi; sg = lowk ? 1.f : -1.f; break;
      case 5: base = lowk ? wvi : wvr; break;
    }
    float4 v = *(const float4*)(base + (size_t)r1 * 1024 + kk);
    unsigned int lo = (unsigned)bfbits(v.x * sg) | ((unsigned)bfbits(v.y * sg) << 16);
    unsigned int hi = (unsigned)bfbits(v.z * sg) | ((unsigned)bfbits(v.w * sg) << 16);
    *(uint2*)(out + (size_t)idx * 4) = make_uint2(lo, hi);
  }
}

__global__ void pack_wo_k(const float* __restrict__ wor, const float* __restrict__ woi,
                          bf16_t* __restrict__ out) {
  const int total4 = 2048 * 2048 / 4;
  for (int idx = blockIdx.x * blockDim.x + threadIdx.x; idx < total4;
       idx += gridDim.x * blockDim.x) {
    int row = idx >> 9, k = (idx & 511) * 4;
    int sec = row >> 10, r1 = row & 1023;
    bool lowk = (k < 1024);
    int kk = lowk ? k : (k - 1024);
    const float* base; float sg = 1.f;
    if (sec == 0) { base = lowk ? wor : woi; sg = lowk ? 1.f : -1.f; }
    else          { base = lowk ? woi : wor; }
    float4 v = *(const float4*)(base + (size_t)r1 * 1024 + kk);
    unsigned int lo = (unsigned)bfbits(v.x * sg) | ((unsigned)bfbits(v.y * sg) << 16);
    unsigned int hi = (unsigned)bfbits(v.z * sg) | ((unsigned)bfbits(v.w * sg) << 16);
    *(uint2*)(out + (size_t)idx * 4) = make_uint2(lo, hi);
  }
}

// ---------------------------------------------------------------- GEMM core, BK=64 + swizzle
// C[m,n] = sum_k A[m,k]*W[n,k]; A: Mx2048, W: Nx2048 bf16 row-major. 128x128 tile.
// LDS row = 64 elem (128 B = 8 chunks of 16 B); LDS[r][c'] holds global chunk c'^(r&7).
__device__ __forceinline__ void gemm_core(const bf16_t* __restrict__ A,
                                          const bf16_t* __restrict__ W,
                                          int m0, int n0, f32x4 (&acc)[4][4]) {
  __shared__ __align__(16) bf16_t sA[128 * 64];
  __shared__ __align__(16) bf16_t sB[128 * 64];
  const int tid = threadIdx.x;
  const int lane = tid & 63, w = tid >> 6;
  const int wr = w >> 1, wc = w & 1;
  const int quad = lane >> 4, m16 = lane & 15;
  // staging geometry: wave w, instr i covers LDS rows [w*32+i*8, +8); lane: rowoff=lane>>3,
  // chunk'=lane&7, global chunk = (lane&7)^(lane>>3)  (row&7 == lane>>3 here)
  const int srow = w * 32 + (lane >> 3);                 // + i*8
  const int gcol = (((lane & 7) ^ (lane >> 3)) * 8);     // global k-offset within tile
  const int swz7 = m16 & 7;                              // frag-read swizzle
  for (int k0 = 0; k0 < 2048; k0 += 64) {
    __syncthreads();
#pragma unroll
    for (int i = 0; i < 4; ++i) {
      gload_lds16(A + (size_t)(m0 + srow + i * 8) * 2048 + k0 + gcol,
                  sA + (size_t)(w * 32 + i * 8) * 64 + lane * 8);
      gload_lds16(W + (size_t)(n0 + srow + i * 8) * 2048 + k0 + gcol,
                  sB + (size_t)(w * 32 + i * 8) * 64 + lane * 8);
    }
    __syncthreads();
#pragma unroll
    for (int kk = 0; kk < 2; ++kk) {
      short8 af[4], bf[4];
#pragma unroll
      for (int i = 0; i < 4; ++i)
        af[i] = *(const short8*)(sA + (wr * 64 + i * 16 + m16) * 64 +
                                 ((kk * 4 + quad) ^ swz7) * 8);
#pragma unroll
      for (int j = 0; j < 4; ++j)
        bf[j] = *(const short8*)(sB + (wc * 64 + j * 16 + m16) * 64 +
                                 ((kk * 4 + quad) ^ swz7) * 8);
#pragma unroll
      for (int i = 0; i < 4; ++i)
#pragma unroll
        for (int j = 0; j < 4; ++j)
          acc[i][j] = __builtin_amdgcn_mfma_f32_16x16x32_bf16(af[i], bf[j], acc[i][j], 0, 0, 0);
    }
  }
}

// QKV GEMM: N=6144. cols 0..4095 -> qk buf [4096][4096] (Qr|Qi|Kr|Ki), Q pre-scaled by 0.125.
// cols 4096..6143 -> V transposed: vt[b*2048 + h*128 + ri*64 + d][seq]
__global__ __launch_bounds__(256) void gemm_qkv_k(const bf16_t* __restrict__ A,
                                                  const bf16_t* __restrict__ W,
                                                  bf16_t* __restrict__ qk,
                                                  bf16_t* __restrict__ vt) {
  f32x4 acc[4][4] = {};
  const int m0 = blockIdx.x * 128, n0 = blockIdx.y * 128;
  gemm_core(A, W, m0, n0, acc);
  const int lane = threadIdx.x & 63, w = threadIdx.x >> 6;
  const int wr = w >> 1, wc = w & 1, quad = lane >> 4, m16 = lane & 15;
#pragma unroll
  for (int i = 0; i < 4; ++i) {
    const int rowb = m0 + wr * 64 + i * 16 + quad * 4;  // C/D row = quad*4 + reg
#pragma unroll
    for (int j = 0; j < 4; ++j) {
      const int col = n0 + wc * 64 + j * 16 + m16;      // C/D col = lane&15
      if (col < 4096) {
        const float sc = (col < 2048) ? 0.125f : 1.f;   // pre-scale Q by SCALE
#pragma unroll
        for (int r = 0; r < 4; ++r)
          qk[(size_t)(rowb + r) * 4096 + col] = __float2bfloat16(acc[i][j][r] * sc);
      } else {
        const int vcol = col - 4096;
        const int ri = vcol >> 10, dfeat = vcol & 1023;
        const int b = rowb >> 11, seq = rowb & 2047;
        const size_t vrow = (size_t)(b * 2048 + (dfeat >> 6) * 128 + ri * 64 + (dfeat & 63));
        unsigned int lo = (unsigned)bfbits(acc[i][j][0]) | ((unsigned)bfbits(acc[i][j][1]) << 16);
        unsigned int hi = (unsigned)bfbits(acc[i][j][2]) | ((unsigned)bfbits(acc[i][j][3]) << 16);
        *(uint2*)(vt + vrow * 2048 + seq) = make_uint2(lo, hi);
      }
    }
  }
}

// Output GEMM: N=2048 ([yr|yi]), fp32 out + bias.
__global__ __launch_bounds__(256) void gemm_out_k(const bf16_t* __restrict__ A,
                                                  const bf16_t* __restrict__ W,
                                                  const float* __restrict__ bor,
                                                  const float* __restrict__ boi,
                                                  float* __restrict__ out) {
  f32x4 acc[4][4] = {};
  const int m0 = blockIdx.x * 128, n0 = blockIdx.y * 128;
  gemm_core(A, W, m0, n0, acc);
  const int lane = threadIdx.x & 63, w = threadIdx.x >> 6;
  const int wr = w >> 1, wc = w & 1, quad = lane >> 4, m16 = lane & 15;
#pragma unroll
  for (int i = 0; i < 4; ++i) {
    const int rowb = m0 + wr * 64 + i * 16 + quad * 4;
#pragma unroll
    for (int j = 0; j < 4; ++j) {
      const int col = n0 + wc * 64 + j * 16 + m16;
      float bias; float* op;
      if (col < 1024) { bias = bor[col]; op = out + col; }
      else            { bias = boi[col - 1024]; op = out + 4194304 + (col - 1024); }
#pragma unroll
      for (int r = 0; r < 4; ++r)
        op[(size_t)(rowb + r) * 1024] = acc[i][j][r] + bias;
    }
  }
}

// ---------------------------------------------------------------- flash attention v3
// grid (16, B*H): block x handles q-subtiles A = x*64.. and B = (31-x)*64.. against a SHARED
// staged K/V tile (joint k-loop, BK=64). Fixed-max softmax, ones-row-MFMA row sums.
// K/V staged via global_load_lds + XOR chunk swizzle; sK stride 128 (16 chunks/row),
// sV stride 64 (8 chunks/row), sP padded 72 (VALU-written, no contract constraint).
__global__ __launch_bounds__(256, 2) void attn_k(const bf16_t* __restrict__ qk,
                                                 const bf16_t* __restrict__ vt,
                                                 bf16_t* __restrict__ acat) {
  __shared__ __align__(16) bf16_t sK[64 * 128];       // 16 KB
  __shared__ __align__(16) bf16_t sV[144 * 64];       // 18 KB (rows 128..143: ones/zeros)
  __shared__ __align__(16) bf16_t sP[4][2][16 * 72];  // 18 KB
  const int tid = threadIdx.x, lane = tid & 63, w = tid >> 6;
  const int quad = lane >> 4, m16 = lane & 15;
  const int x = blockIdx.x, bh = blockIdx.y, b = bh >> 4, h = bh & 15;
  const size_t qkrow0 = (size_t)b * 2048;
  const int qA = x * 64, qB = (31 - x) * 64;
  const int nT = 32 - x;
  const int swz7 = m16 & 7;

  // preset sV rows 128..143: row 128 = ones, rest zeros (constant rows: swizzle-invariant)
  {
    const int rr = tid >> 4, cb = (tid & 15) * 4;
    const bf16_t v = __float2bfloat16(rr == 0 ? 1.f : 0.f);
#pragma unroll
    for (int i = 0; i < 4; ++i) sV[(128 + rr) * 64 + cb + i] = v;
  }

  // Q fragments for both subtiles (A-operand: m=lane&15, k=quad*8+j), d-chunks of 32
  short8 qfA[4], qfB[4];
  {
    const bf16_t* qa = qk + (qkrow0 + qA + w * 16 + m16) * 4096;
    const bf16_t* qb = qk + (qkrow0 + qB + w * 16 + m16) * 4096;
#pragma unroll
    for (int kk = 0; kk < 4; ++kk) {
      const int col = (kk >> 1) * 1024 + h * 64 + (kk & 1) * 32 + quad * 8;
      qfA[kk] = *(const short8*)(qa + col);
      qfB[kk] = *(const short8*)(qb + col);
    }
  }
  f32x4 oA[9], oB[9];
#pragma unroll
  for (int j = 0; j < 9; ++j) { oA[j] = (f32x4){0.f,0.f,0.f,0.f}; oB[j] = (f32x4){0.f,0.f,0.f,0.f}; }

  const int qrowA = qA + w * 16 + quad * 4;
  const int qrowB = qB + w * 16 + quad * 4;

  // staging geometry
  const int kl4 = lane >> 4, kl15 = lane & 15;   // K tile: 4 rows/instr (256 B rows)
  const int vl3 = lane >> 3;                     // V tile: 8 rows/instr (128 B rows)
  const int vg7 = ((lane & 7) ^ vl3) * 8;

  for (int t = 0; t < nT; ++t) {
    const int k0 = t * 64;
    __syncthreads();
    // stage K: 64 rows x 128 elem (Kr|Ki of head h); row&7 = (i*4 + lane>>4)&7
#pragma unroll
    for (int i = 0; i < 4; ++i) {
      const int row = w * 16 + i * 4 + kl4;
      const int g = kl15 ^ (row & 7);            // low-3 XOR; bit3 of kl15 preserved
      const int col = 2048 + (g >> 3) * 1024 + h * 64 + (g & 7) * 8;
      gload_lds16(qk + (qkrow0 + k0 + row) * 4096 + col,
                  sK + (size_t)(w * 16 + i * 4) * 128 + lane * 8);
    }
    // stage V^T: 128 d-rows x 64 k; row&7 = lane>>3
#pragma unroll
    for (int i = 0; i < 4; ++i) {
      const int row = w * 32 + i * 8 + vl3;
      gload_lds16(vt + ((size_t)bh * 128 + row) * 2048 + k0 + vg7,
                  sV + (size_t)(w * 32 + i * 8) * 64 + lane * 8);
    }
    __syncthreads();

    const bool aAct = (t <= x);
    const bool dgA = (t == x), dgB = (t == nT - 1);

    // ---- S = Qs·K^T; joint over both subtiles per K-frag read
    f32x4 sAv[4], sBv[4];
    if (aAct) {
#pragma unroll
      for (int jt = 0; jt < 4; ++jt) {
        f32x4 a1 = (f32x4){0.f,0.f,0.f,0.f}, a2 = (f32x4){0.f,0.f,0.f,0.f};
#pragma unroll
        for (int kk = 0; kk < 4; ++kk) {
          short8 kf = *(const short8*)(sK + (jt * 16 + m16) * 128 +
                                       ((kk * 4 + quad) ^ swz7) * 8);
          a1 = __builtin_amdgcn_mfma_f32_16x16x32_bf16(qfA[kk], kf, a1, 0, 0, 0);
          a2 = __builtin_amdgcn_mfma_f32_16x16x32_bf16(qfB[kk], kf, a2, 0, 0, 0);
        }
        sAv[jt] = a1; sBv[jt] = a2;
      }
    } else {
#pragma unroll
      for (int jt = 0; jt < 4; ++jt) {
        f32x4 a2 = (f32x4){0.f,0.f,0.f,0.f};
#pragma unroll
        for (int kk = 0; kk < 4; ++kk) {
          short8 kf = *(const short8*)(sK + (jt * 16 + m16) * 128 +
                                       ((kk * 4 + quad) ^ swz7) * 8);
          a2 = __builtin_amdgcn_mfma_f32_16x16x32_bf16(qfB[kk], kf, a2, 0, 0, 0);
        }
        sBv[jt] = a2;
      }
    }

    // ---- fixed-max softmax: P = exp(S), C-layout -> A-layout via per-wave sP
    if (aAct) {
      bf16_t* pw = sP[w][0];
#pragma unroll
      for (int jt = 0; jt < 4; ++jt)
#pragma unroll
        for (int r = 0; r < 4; ++r) {
          float s = sAv[jt][r];
          if (dgA && (k0 + jt * 16 + m16 > qrowA + r)) s = -1e30f;
          pw[(quad * 4 + r) * 72 + jt * 16 + m16] = __float2bfloat16(__expf(s));
        }
    }
    {
      bf16_t* pw = sP[w][1];
#pragma unroll
      for (int jt = 0; jt < 4; ++jt)
#pragma unroll
        for (int r = 0; r < 4; ++r) {
          float s = sBv[jt][r];
          if (dgB && (k0 + jt * 16 + m16 > qrowB + r)) s = -1e30f;
          pw[(quad * 4 + r) * 72 + jt * 16 + m16] = __float2bfloat16(__expf(s));
        }
    }
    asm volatile("s_waitcnt lgkmcnt(0)" ::: "memory");  // own-wave P write->read

    // ---- O += P·V (j=8 = ones-row -> row sums l); joint per V-frag read
    if (aAct) {
#pragma unroll
      for (int kc = 0; kc < 2; ++kc) {
        short8 pA = *(const short8*)(sP[w][0] + m16 * 72 + kc * 32 + quad * 8);
        short8 pB = *(const short8*)(sP[w][1] + m16 * 72 + kc * 32 + quad * 8);
#pragma unroll
        for (int j = 0; j < 9; ++j) {
          short8 vf = *(const short8*)(sV + (j * 16 + m16) * 64 +
                                       ((kc * 4 + quad) ^ swz7) * 8);
          oA[j] = __builtin_amdgcn_mfma_f32_16x16x32_bf16(pA, vf, oA[j], 0, 0, 0);
          oB[j] = __builtin_amdgcn_mfma_f32_16x16x32_bf16(pB, vf, oB[j], 0, 0, 0);
        }
      }
    } else {
#pragma unroll
      for (int kc = 0; kc < 2; ++kc) {
        short8 pB = *(const short8*)(sP[w][1] + m16 * 72 + kc * 32 + quad * 8);
#pragma unroll
        for (int j = 0; j < 9; ++j) {
          short8 vf = *(const short8*)(sV + (j * 16 + m16) * 64 +
                                       ((kc * 4 + quad) ^ swz7) * 8);
          oB[j] = __builtin_amdgcn_mfma_f32_16x16x32_bf16(pB, vf, oB[j], 0, 0, 0);
        }
      }
    }
  }

  // ---- epilogue: l broadcast from lane (quad*16), normalize, write [B,L,2048]=[out_r|out_i]
#pragma unroll
  for (int part = 0; part < 2; ++part) {
    f32x4* o = part ? oB : oA;
    const int qrow = part ? qrowB : qrowA;
    float inv[4];
#pragma unroll
    for (int r = 0; r < 4; ++r)
      inv[r] = 1.f / __shfl(o[8][r], lane & 48);
#pragma unroll
    for (int j = 0; j < 8; ++j) {
      const int d = j * 16 + m16;
      const int col = (d < 64) ? (h * 64 + d) : (1024 + h * 64 + (d - 64));
#pragma unroll
      for (int r = 0; r < 4; ++r)
        acat[((size_t)b * 2048 + qrow + r) * 2048 + col] = __float2bfloat16(o[j][r] * inv[r]);
    }
  }
}

// ---------------------------------------------------------------- launch
extern "C" void kernel_launch(void* const* d_in, const int* in_sizes, int n_in,
                              void* d_out, int out_size, void* d_ws, size_t ws_size,
                              hipStream_t stream) {
  const float* xr  = (const float*)d_in[0];
  const float* xi  = (const float*)d_in[1];
  const float* wqr = (const float*)d_in[2];
  const float* wqi = (const float*)d_in[3];
  const float* wkr = (const float*)d_in[4];
  const float* wki = (const float*)d_in[5];
  const float* wvr = (const float*)d_in[6];
  const float* wvi = (const float*)d_in[7];
  const float* wor = (const float*)d_in[8];
  const float* woi = (const float*)d_in[9];
  const float* bor = (const float*)d_in[10];
  const float* boi = (const float*)d_in[11];
  float* out = (float*)d_out;

  char* ws = (char*)d_ws;
  bf16_t* Xcat = (bf16_t*)(ws);                   // 4096x2048   16 MB
  bf16_t* Wqkv = (bf16_t*)(ws + 16777216ull);     // 6144x2048   24 MB
  bf16_t* QKb  = (bf16_t*)(ws + 41943040ull);     // 4096x4096   32 MB
  bf16_t* Vt   = (bf16_t*)(ws + 75497472ull);     // 4096x2048   16 MB (V transposed)
  bf16_t* Acat = (bf16_t*)(ws + 92274688ull);     // 4096x2048   16 MB
  bf16_t* Wo   = (bf16_t*)(ws + 109051904ull);    // 2048x2048    8 MB

  pack_x_k<<<2048, 256, 0, stream>>>(xr, xi, Xcat);
  pack_wqkv_k<<<2048, 256, 0, stream>>>(wqr, wqi, wkr, wki, wvr, wvi, Wqkv);
  pack_wo_k<<<1024, 256, 0, stream>>>(wor, woi, Wo);
  gemm_qkv_k<<<dim3(32, 48), 256, 0, stream>>>(Xcat, Wqkv, QKb, Vt);
  attn_k<<<dim3(16, 32), 256, 0, stream>>>(QKb, Vt, Acat);
  gemm_out_k<<<dim3(32, 16), 256, 0, stream>>>(Acat, Wo, bor, boi, out);
}